// Round 1
// baseline (484.647 us; speedup 1.0000x reference)
//
#include <hip/hip_runtime.h>

#define B 16
#define C 256
#define BC (B * C)
#define SPATIAL 4096   // 64*64 spatial sites per (b,c); each site is one float4 (4 comps)

typedef float vf4 __attribute__((ext_vector_type(4)));

// ---------------- Kernel 1: wave-per-slice global max-pool ------------------
// One 64-lane wave owns one (b,c) slice (4096 float4 = 64 KiB).
// No LDS, no barriers: 64 coalesced float4 loads per lane, then a pure
// shfl_down wave reduce. Grid = BC/4 blocks x 256 threads (4 waves/block).
__global__ __launch_bounds__(256) void pool_kernel(const float4* __restrict__ x4,
                                                   float4* __restrict__ pooled4) {
    const int wid  = threadIdx.x >> 6;
    const int lane = threadIdx.x & 63;
    const int bc   = (blockIdx.x << 2) + wid;      // 0 .. BC-1
    const float4* p = x4 + (size_t)bc * SPATIAL;

    float4 m = p[lane];
    #pragma unroll 7
    for (int k = 1; k < 64; ++k) {                 // 63 iters, 7x9 unroll blocks
        float4 v = p[lane + (k << 6)];
        m.x = fmaxf(m.x, v.x);
        m.y = fmaxf(m.y, v.y);
        m.z = fmaxf(m.z, v.z);
        m.w = fmaxf(m.w, v.w);
    }

    #pragma unroll
    for (int off = 32; off > 0; off >>= 1) {
        m.x = fmaxf(m.x, __shfl_down(m.x, off));
        m.y = fmaxf(m.y, __shfl_down(m.y, off));
        m.z = fmaxf(m.z, __shfl_down(m.z, off));
        m.w = fmaxf(m.w, __shfl_down(m.w, off));
    }
    if (lane == 0) pooled4[bc] = m;
}

// ---------------- Kernel 2: compute all quaternion scales ONCE --------------
// 16 blocks (one per batch) x 256 threads (one per output channel).
// comp_w: (4,1,C) -> comp_w[comp*C + i]
// comp_b: (4,1)   -> comp_b[comp]
// exc_w : (4,C,1) -> exc_w[comp*C + o]
// exc_b : (4,C)   -> exc_b[comp*C + o]
__global__ __launch_bounds__(256) void scales_kernel(const float4* __restrict__ pooled4,
                                                     const float* __restrict__ comp_w,
                                                     const float* __restrict__ comp_b,
                                                     const float* __restrict__ exc_w,
                                                     const float* __restrict__ exc_b,
                                                     float4* __restrict__ s4) {
    const int b   = blockIdx.x;
    const int tid = threadIdx.x;                   // == input channel i and output channel c

    // squeeze: dot(pooled[b,:,:], comp_w) over 256 channels
    float4 p = pooled4[b * C + tid];
    float4 prod;
    prod.x = p.x * comp_w[0 * C + tid];
    prod.y = p.y * comp_w[1 * C + tid];
    prod.z = p.z * comp_w[2 * C + tid];
    prod.w = p.w * comp_w[3 * C + tid];

    #pragma unroll
    for (int off = 32; off > 0; off >>= 1) {
        prod.x += __shfl_down(prod.x, off);
        prod.y += __shfl_down(prod.y, off);
        prod.z += __shfl_down(prod.z, off);
        prod.w += __shfl_down(prod.w, off);
    }

    __shared__ float4 lsum[4];
    const int lane = tid & 63, wid = tid >> 6;
    if (lane == 0) lsum[wid] = prod;
    __syncthreads();

    const float r  = lsum[0].x + lsum[1].x + lsum[2].x + lsum[3].x + comp_b[0];
    const float xc = lsum[0].y + lsum[1].y + lsum[2].y + lsum[3].y + comp_b[1];
    const float yc = lsum[0].z + lsum[1].z + lsum[2].z + lsum[3].z + comp_b[2];
    const float zc = lsum[0].w + lsum[1].w + lsum[2].w + lsum[3].w + comp_b[3];

    // Hamilton-style combine #1 (Cout = 1)
    const float u0 = r + xc + yc + zc;
    const float u1 = xc - r - zc + yc;
    const float u2 = yc + zc - r - xc;
    const float u3 = zc - yc + xc - r;

    // excite linear, this thread's output channel c = tid (Cin = 1)
    const int c = tid;
    const float c0 = u0 * exc_w[0 * C + c] + exc_b[0 * C + c];
    const float c1 = u1 * exc_w[1 * C + c] + exc_b[1 * C + c];
    const float c2 = u2 * exc_w[2 * C + c] + exc_b[2 * C + c];
    const float c3 = u3 * exc_w[3 * C + c] + exc_b[3 * C + c];

    // Hamilton-style combine #2 -> per-(b,c) quaternion scale
    float4 s;
    s.x = c0 + c1 + c2 + c3;
    s.y = c1 - c0 - c3 + c2;
    s.z = c2 + c3 - c0 - c1;
    s.w = c3 - c2 + c1 - c0;
    s4[b * C + c] = s;
}

// ---------------- Kernel 3: pure broadcast multiply -------------------------
// Zero prologue: the per-(b,c) scale is a wave-uniform scalar load (s_load),
// then a barrier-free load*mul*NT-store stream. Reversed bc order so we read
// the tail of x (most recently L3-resident from pool_kernel) first.
__global__ __launch_bounds__(256) void mul_kernel(const float4* __restrict__ x4,
                                                  const float4* __restrict__ s4,
                                                  float4* __restrict__ out4) {
    const int bc = (BC - 1) - blockIdx.x;          // reversed traversal

    const float4 sf = s4[bc];                      // uniform -> scalar load
    vf4 s;
    s.x = sf.x; s.y = sf.y; s.z = sf.z; s.w = sf.w;

    const vf4* xp = (const vf4*)(x4 + (size_t)bc * SPATIAL);
    vf4*       op = (vf4*)(out4 + (size_t)bc * SPATIAL);

    #pragma unroll 8
    for (int i = threadIdx.x; i < SPATIAL; i += 256) {
        vf4 v = xp[i];
        v *= s;
        __builtin_nontemporal_store(v, op + i);
    }
}

extern "C" void kernel_launch(void* const* d_in, const int* in_sizes, int n_in,
                              void* d_out, int out_size, void* d_ws, size_t ws_size,
                              hipStream_t stream) {
    const float4* x4     = (const float4*)d_in[0];
    const float*  comp_w = (const float*)d_in[1];
    const float*  comp_b = (const float*)d_in[2];
    const float*  exc_w  = (const float*)d_in[3];
    const float*  exc_b  = (const float*)d_in[4];
    float4* out4 = (float4*)d_out;

    float4* pooled4 = (float4*)d_ws;               // BC float4 = 64 KiB
    float4* s4      = pooled4 + BC;                // BC float4 = 64 KiB

    pool_kernel<<<BC / 4, 256, 0, stream>>>(x4, pooled4);
    scales_kernel<<<B, 256, 0, stream>>>(pooled4, comp_w, comp_b, exc_w, exc_b, s4);
    mul_kernel<<<BC, 256, 0, stream>>>(x4, s4, out4);
}